// Round 2
// baseline (155.674 us; speedup 1.0000x reference)
//
#include <hip/hip_runtime.h>

// Problem constants
#define BATCH  4
#define SEQL   2048
#define DMODEL 1024
#define NST    16
#define CT     64            // chunk length T
#define NCH    (SEQL / CT)   // 32 chunks
#define QSEG   16            // sigma/tau segment length (4 segments per chunk)
#define CSLICE (BATCH * NCH * DMODEL * NST)   // 2,097,152 floats per partial slice

// ws layout (float offsets)
#define WS_P     0           // P[sigma][m]   = (A^(T-1-sigma) B)[m]      : CT*16
#define WS_W     1024        // W[tau][m]     = (B^T A^(tau+1))[m]        : CT*16
#define WS_KV    2048        // kvext[127], kvext[63+d] = B^T A^d B, 0 for d<0 (pad to 128)
#define WS_APOW  2176        // Apow[m][k]    = (A^CT)[m][k]              : 256
#define WS_HIN   4096        // hin[b][j][d][m] = s_{j-1}                 : B*NCH*D*16

// ---------------------------------------------------------------------------
// Setup: block delta (0..64) computes A^delta in fp64 via binary powering,
// then emits its slice of the tables.
// ---------------------------------------------------------------------------
__global__ __launch_bounds__(256) void setup_tables(const float* __restrict__ A,
                                                    const float* __restrict__ Bv,
                                                    float* __restrict__ ws) {
    __shared__ double buf0[256], buf1[256], buf2[256], buf3[256];
    __shared__ double bd[16], vtmp[16];
    double* S  = buf0;
    double* R  = buf1;
    double* Ta = buf2;
    double* Tb = buf3;
    const int t  = threadIdx.x;
    const int i  = t >> 4;
    const int kk = t & 15;
    const int delta = blockIdx.x;   // 0..64

    S[t] = (double)A[t];
    R[t] = (i == kk) ? 1.0 : 0.0;
    if (t < 16) bd[t] = (double)Bv[t];
    __syncthreads();

    for (int sb = 0; sb < 7; ++sb) {
        if ((delta >> sb) & 1) {
            double acc = 0.0;
            #pragma unroll
            for (int l = 0; l < 16; ++l) acc += R[i * 16 + l] * S[l * 16 + kk];
            Ta[t] = acc;
            __syncthreads();
            double* tmp = R; R = Ta; Ta = tmp;
        }
        if (sb < 6) {
            double acc = 0.0;
            #pragma unroll
            for (int l = 0; l < 16; ++l) acc += S[i * 16 + l] * S[l * 16 + kk];
            Tb[t] = acc;
            __syncthreads();
            double* tmp = S; S = Tb; Tb = tmp;
        }
    }
    // R now holds A^delta (fp64)

    if (delta < CT) {
        if (t < 16) {   // m = t : P[CT-1-delta][m] = (A^delta B)[m]
            double acc = 0.0;
            #pragma unroll
            for (int k = 0; k < 16; ++k) acc += R[t * 16 + k] * bd[k];
            ws[WS_P + (CT - 1 - delta) * 16 + t] = (float)acc;
            vtmp[t] = acc;
        }
        __syncthreads();
        if (t == 0) {   // k_delta = B^T A^delta B
            double kd = 0.0;
            for (int m = 0; m < 16; ++m) kd += bd[m] * vtmp[m];
            ws[WS_KV + 63 + delta] = (float)kd;
        }
    }
    if (delta >= 1 && t < 16) {   // W[delta-1][m] = sum_n B[n] (A^delta)[n][m]
        double acc = 0.0;
        #pragma unroll
        for (int n = 0; n < 16; ++n) acc += bd[n] * R[n * 16 + t];
        ws[WS_W + (delta - 1) * 16 + t] = (float)acc;
    }
    if (delta == CT) ws[WS_APOW + t] = (float)R[t];   // A^CT carry matrix
    if (delta == 0 && t < 63) ws[WS_KV + t] = 0.0f;   // zero-pad negative lags
}

// ---------------------------------------------------------------------------
// K1: 4-way sigma-split partial chunk states.
// Block (b, j, q, dblk): partial_q[m] = sum_{s=16q..16q+15} P[s][m] x[s].
// 2048 blocks -> 32 waves/CU.
// ---------------------------------------------------------------------------
__global__ __launch_bounds__(256) void k1_chunkstate(const float* __restrict__ x,
                                                     const float* __restrict__ ws,
                                                     float* __restrict__ cbuf) {
    const int blk  = blockIdx.x;          // 2048 blocks
    const int b    = blk >> 9;            // 4
    const int j    = (blk >> 4) & 31;     // 32
    const int q    = (blk >> 2) & 3;      // 4 sigma segments
    const int dblk = blk & 3;             // 4
    const int d    = dblk * 256 + threadIdx.x;

    const float* P = ws + WS_P + q * QSEG * 16;  // wave-uniform -> s_load
    float c[16];
    #pragma unroll
    for (int m = 0; m < 16; ++m) c[m] = 0.0f;

    const float* xp = x + ((size_t)(b * SEQL + j * CT + q * QSEG)) * DMODEL + d;
    #pragma unroll
    for (int s = 0; s < QSEG; ++s) {
        float xv = xp[(size_t)s * DMODEL];
        #pragma unroll
        for (int m = 0; m < 16; ++m) c[m] = fmaf(P[s * 16 + m], xv, c[m]);
    }

    float4* outp = (float4*)(cbuf + (size_t)q * CSLICE +
                             (((size_t)(b * NCH + j) * DMODEL) + d) * 16);
    #pragma unroll
    for (int qq = 0; qq < 4; ++qq)
        outp[qq] = make_float4(c[4 * qq], c[4 * qq + 1], c[4 * qq + 2], c[4 * qq + 3]);
}

// ---------------------------------------------------------------------------
// K2: carry scan over chunks. Thread = (channel, state component m).
// s_j = Apow * s_{j-1} + sum_q partial_q ; h_in_j = s_{j-1} written to ws.
// Software-pipelined: chunk j+1's partials load while chunk j's chain runs.
// ---------------------------------------------------------------------------
__global__ __launch_bounds__(256) void k2_carry(const float* __restrict__ cbuf,
                                                float* __restrict__ ws) {
    const int blk = blockIdx.x;           // 256 blocks
    const int b   = blk >> 6;             // 4
    const int d0  = (blk & 63) * 16;
    const int t   = threadIdx.x;
    const int m   = t & 15;
    const int ch  = t >> 4;               // 0..15 in block
    const int d   = d0 + ch;
    const int laneBase = t & 48;          // 16-lane group base within wave

    float Arow[16];
    #pragma unroll
    for (int k = 0; k < 16; ++k) Arow[k] = ws[WS_APOW + m * 16 + k];

    float* hin = ws + WS_HIN;
    const size_t base0 = (((size_t)(b * NCH) * DMODEL) + d) * 16 + m;
    const size_t jstride = (size_t)DMODEL * 16;

    // preload chunk 0 partials
    float c0 = cbuf[base0];
    float c1 = cbuf[base0 + 1 * CSLICE];
    float c2 = cbuf[base0 + 2 * CSLICE];
    float c3 = cbuf[base0 + 3 * CSLICE];

    float s = 0.0f;
    for (int j = 0; j < NCH; ++j) {
        const size_t base = base0 + (size_t)j * jstride;
        float n0 = 0.f, n1 = 0.f, n2 = 0.f, n3 = 0.f;
        if (j + 1 < NCH) {                // prefetch next chunk (independent)
            const size_t nb = base + jstride;
            n0 = cbuf[nb];
            n1 = cbuf[nb + 1 * CSLICE];
            n2 = cbuf[nb + 2 * CSLICE];
            n3 = cbuf[nb + 3 * CSLICE];
        }
        hin[base] = s;                    // h_in for chunk j = s_{j-1}
        float acc = (c0 + c1) + (c2 + c3);
        #pragma unroll
        for (int k = 0; k < 16; ++k)
            acc = fmaf(Arow[k], __shfl(s, laneBase + k, 64), acc);
        s = acc;
        c0 = n0; c1 = n1; c2 = n2; c3 = n3;
    }
}

// ---------------------------------------------------------------------------
// K3: outputs, 4-way tau-split. Block (b, j, tt, dblk) computes taus
// [16tt, 16tt+16): y[tau] = W[tau].h_in + sum_{s<=tau} k[tau-s] x[s].
// 2048 blocks -> 32 waves/CU.
// ---------------------------------------------------------------------------
__global__ __launch_bounds__(256) void k3_output(const float* __restrict__ x,
                                                 const float* __restrict__ ws,
                                                 float* __restrict__ y) {
    const int blk  = blockIdx.x;          // 2048 blocks
    const int b    = blk >> 9;
    const int j    = (blk >> 4) & 31;
    const int tt   = (blk >> 2) & 3;      // tau tile
    const int dblk = blk & 3;
    const int d    = dblk * 256 + threadIdx.x;

    const float* W  = ws + WS_W + tt * QSEG * 16;
    const float* kv = ws + WS_KV;         // kvext: index 63 + lag
    const float* hinp = ws + WS_HIN + (((size_t)(b * NCH + j) * DMODEL) + d) * 16;

    float h[16];
    #pragma unroll
    for (int q = 0; q < 4; ++q) {
        float4 v = ((const float4*)hinp)[q];
        h[4 * q] = v.x; h[4 * q + 1] = v.y; h[4 * q + 2] = v.z; h[4 * q + 3] = v.w;
    }

    float yv[QSEG];
    #pragma unroll
    for (int i = 0; i < QSEG; ++i) {      // correction: W[tau] . h_in
        float acc = 0.0f;
        #pragma unroll
        for (int m = 0; m < 16; ++m) acc = fmaf(W[i * 16 + m], h[m], acc);
        yv[i] = acc;
    }

    const float* xp = x + ((size_t)(b * SEQL + j * CT)) * DMODEL + d;
    const int lim = QSEG * tt + QSEG;
    for (int s = 0; s < lim; ++s) {       // triangle; kv reads are uniform
        float xv = xp[(size_t)s * DMODEL];
        #pragma unroll
        for (int i = 0; i < QSEG; ++i)
            yv[i] = fmaf(kv[63 + tt * QSEG + i - s], xv, yv[i]);
    }

    float* yp = y + ((size_t)(b * SEQL + j * CT + tt * QSEG)) * DMODEL + d;
    #pragma unroll
    for (int i = 0; i < QSEG; ++i) yp[(size_t)i * DMODEL] = yv[i];
}

// ---------------------------------------------------------------------------
extern "C" void kernel_launch(void* const* d_in, const int* in_sizes, int n_in,
                              void* d_out, int out_size, void* d_ws, size_t ws_size,
                              hipStream_t stream) {
    (void)in_sizes; (void)n_in; (void)out_size; (void)ws_size;
    const float* x  = (const float*)d_in[0];
    const float* A  = (const float*)d_in[1];
    const float* Bv = (const float*)d_in[2];
    float* out = (float*)d_out;
    float* ws  = (float*)d_ws;

    // 4 partial-c slices exactly fill d_out (4 * 2,097,152 = 8,388,608 floats);
    // K3 overwrites d_out with y afterwards. h_in + tables live in ws.
    setup_tables<<<65, 256, 0, stream>>>(A, Bv, ws);
    k1_chunkstate<<<2048, 256, 0, stream>>>(x, ws, out);
    k2_carry<<<256, 256, 0, stream>>>(out, ws);
    k3_output<<<2048, 256, 0, stream>>>(x, ws, out);
}

// Round 3
// 122.154 us; speedup vs baseline: 1.2744x; 1.2744x over previous
//
#include <hip/hip_runtime.h>

// Problem constants
#define BATCH  4
#define SEQL   2048
#define DMODEL 1024
#define NST    16
#define CT     64            // chunk length T
#define NCH    (SEQL / CT)   // 32 chunks
#define QSEG   16            // tau segment length (4 segments per chunk)

// ws layout (float offsets)
#define WS_P     0           // P[sigma][m]   = (A^(T-1-sigma) B)[m]      : CT*16
#define WS_W     1024        // W[tau][m]     = (B^T A^(tau+1))[m]        : CT*16
#define WS_KV    2048        // kvext[127], kvext[63+d] = B^T A^d B, 0 for d<0
#define WS_APOW  2176        // Apow[m][k]    = (A^CT)[m][k]              : 256
#define WS_HIN   4096        // hin[b][j][d][m] = s_{j-1}                 : B*NCH*D*16

// ---------------------------------------------------------------------------
// Setup: block delta (0..64) computes A^delta in fp64 via binary powering,
// then emits its slice of the tables.
// ---------------------------------------------------------------------------
__global__ __launch_bounds__(256) void setup_tables(const float* __restrict__ A,
                                                    const float* __restrict__ Bv,
                                                    float* __restrict__ ws) {
    __shared__ double buf0[256], buf1[256], buf2[256], buf3[256];
    __shared__ double bd[16], vtmp[16];
    double* S  = buf0;
    double* R  = buf1;
    double* Ta = buf2;
    double* Tb = buf3;
    const int t  = threadIdx.x;
    const int i  = t >> 4;
    const int kk = t & 15;
    const int delta = blockIdx.x;   // 0..64

    S[t] = (double)A[t];
    R[t] = (i == kk) ? 1.0 : 0.0;
    if (t < 16) bd[t] = (double)Bv[t];
    __syncthreads();

    for (int sb = 0; sb < 7; ++sb) {
        if ((delta >> sb) & 1) {
            double acc = 0.0;
            #pragma unroll
            for (int l = 0; l < 16; ++l) acc += R[i * 16 + l] * S[l * 16 + kk];
            Ta[t] = acc;
            __syncthreads();
            double* tmp = R; R = Ta; Ta = tmp;
        }
        if (sb < 6) {
            double acc = 0.0;
            #pragma unroll
            for (int l = 0; l < 16; ++l) acc += S[i * 16 + l] * S[l * 16 + kk];
            Tb[t] = acc;
            __syncthreads();
            double* tmp = S; S = Tb; Tb = tmp;
        }
    }
    // R now holds A^delta (fp64)

    if (delta < CT) {
        if (t < 16) {   // m = t : P[CT-1-delta][m] = (A^delta B)[m]
            double acc = 0.0;
            #pragma unroll
            for (int k = 0; k < 16; ++k) acc += R[t * 16 + k] * bd[k];
            ws[WS_P + (CT - 1 - delta) * 16 + t] = (float)acc;
            vtmp[t] = acc;
        }
        __syncthreads();
        if (t == 0) {   // k_delta = B^T A^delta B
            double kd = 0.0;
            for (int m = 0; m < 16; ++m) kd += bd[m] * vtmp[m];
            ws[WS_KV + 63 + delta] = (float)kd;
        }
    }
    if (delta >= 1 && t < 16) {   // W[delta-1][m] = sum_n B[n] (A^delta)[n][m]
        double acc = 0.0;
        #pragma unroll
        for (int n = 0; n < 16; ++n) acc += bd[n] * R[n * 16 + t];
        ws[WS_W + (delta - 1) * 16 + t] = (float)acc;
    }
    if (delta == CT) ws[WS_APOW + t] = (float)R[t];   // A^CT carry matrix
    if (delta == 0 && t < 63) ws[WS_KV + t] = 0.0f;   // zero-pad negative lags
}

// ---------------------------------------------------------------------------
// K1: full chunk state, 512 blocks. Double-buffered 8-wide x-load batches
// keep ~8-16 loads in flight per thread.
// c_j[m] = sum_{sigma} P[sigma][m] x[sigma]
// ---------------------------------------------------------------------------
__global__ __launch_bounds__(256) void k1_chunkstate(const float* __restrict__ x,
                                                     const float* __restrict__ ws,
                                                     float* __restrict__ cbuf) {
    const int blk  = blockIdx.x;          // 512 blocks
    const int b    = blk >> 7;
    const int j    = (blk >> 2) & 31;
    const int dblk = blk & 3;
    const int d    = dblk * 256 + threadIdx.x;

    const float* P  = ws + WS_P;          // wave-uniform -> s_load
    const float* xp = x + ((size_t)(b * SEQL + j * CT)) * DMODEL + d;

    float c[16];
    #pragma unroll
    for (int m = 0; m < 16; ++m) c[m] = 0.0f;

    float xa[8], xb[8];
    #pragma unroll
    for (int s = 0; s < 8; ++s) xa[s] = xp[(size_t)s * DMODEL];

    #pragma unroll
    for (int g = 0; g < 8; ++g) {         // 8 batches of 8 sigma
        float* cur = (g & 1) ? xb : xa;
        float* nxt = (g & 1) ? xa : xb;
        if (g < 7) {
            #pragma unroll
            for (int s = 0; s < 8; ++s)
                nxt[s] = xp[(size_t)((g + 1) * 8 + s) * DMODEL];
        }
        #pragma unroll
        for (int s = 0; s < 8; ++s) {
            const int ss = g * 8 + s;
            #pragma unroll
            for (int m = 0; m < 16; ++m)
                c[m] = fmaf(P[ss * 16 + m], cur[s], c[m]);
        }
    }

    float4* outp = (float4*)(cbuf + (((size_t)(b * NCH + j) * DMODEL) + d) * 16);
    #pragma unroll
    for (int q = 0; q < 4; ++q)
        outp[q] = make_float4(c[4 * q], c[4 * q + 1], c[4 * q + 2], c[4 * q + 3]);
}

// ---------------------------------------------------------------------------
// K2: carry scan over chunks. Thread = (channel d, state component m).
// ALL 32 chunk partials are prefetched upfront (independent loads, ~8 MB in
// flight across the grid -> full-BW streaming), then the serial shfl chain
// runs from registers. s_j = Apow*s_{j-1} + c_j ; hin_j = s_{j-1}.
// ---------------------------------------------------------------------------
__global__ __launch_bounds__(256) void k2_carry(const float* __restrict__ cbuf,
                                                float* __restrict__ ws) {
    const int blk = blockIdx.x;           // 256 blocks
    const int b   = blk >> 6;
    const int d0  = (blk & 63) * 16;
    const int t   = threadIdx.x;
    const int m   = t & 15;
    const int ch  = t >> 4;
    const int d   = d0 + ch;
    const int laneBase = t & 48;          // 16-lane group base within wave

    const size_t base0   = (((size_t)(b * NCH) * DMODEL) + d) * 16 + m;
    const size_t jstride = (size_t)DMODEL * 16;

    float cpre[NCH];
    #pragma unroll
    for (int j = 0; j < NCH; ++j)
        cpre[j] = cbuf[base0 + (size_t)j * jstride];

    float Arow[16];
    #pragma unroll
    for (int k = 0; k < 16; ++k) Arow[k] = ws[WS_APOW + m * 16 + k];

    float* hin = ws + WS_HIN;
    float s = 0.0f;
    #pragma unroll
    for (int j = 0; j < NCH; ++j) {
        hin[base0 + (size_t)j * jstride] = s;
        float acc = cpre[j];
        #pragma unroll
        for (int k = 0; k < 16; ++k)
            acc = fmaf(Arow[k], __shfl(s, laneBase + k, 64), acc);
        s = acc;
    }
}

// ---------------------------------------------------------------------------
// K3: outputs, 4-way tau-split with COMPILE-TIME triangle depth (template)
// so the x-load stream fully unrolls and pipelines.
// y[tau] = W[tau].h_in + sum_{s<=tau} k[tau-s] x[s]
// ---------------------------------------------------------------------------
template <int TT>
__device__ __forceinline__ void k3_body(const float* __restrict__ x,
                                        const float* __restrict__ ws,
                                        float* __restrict__ y,
                                        int b, int j, int d) {
    constexpr int LIM = (TT + 1) * QSEG;  // triangle depth: 16/32/48/64
    const float* W  = ws + WS_W + TT * QSEG * 16;
    const float* kv = ws + WS_KV;
    const float* hinp = ws + WS_HIN + (((size_t)(b * NCH + j) * DMODEL) + d) * 16;
    const float* xp = x + ((size_t)(b * SEQL + j * CT)) * DMODEL + d;

    // issue h_in loads and first x batch together
    float4 hv[4];
    #pragma unroll
    for (int q = 0; q < 4; ++q) hv[q] = ((const float4*)hinp)[q];
    float xa[8], xb[8];
    #pragma unroll
    for (int s = 0; s < 8; ++s) xa[s] = xp[(size_t)s * DMODEL];

    float h[16];
    #pragma unroll
    for (int q = 0; q < 4; ++q) {
        h[4 * q] = hv[q].x; h[4 * q + 1] = hv[q].y;
        h[4 * q + 2] = hv[q].z; h[4 * q + 3] = hv[q].w;
    }

    float yv[QSEG];
    #pragma unroll
    for (int i = 0; i < QSEG; ++i) {      // correction: W[tau] . h_in
        float acc = 0.0f;
        #pragma unroll
        for (int mm = 0; mm < 16; ++mm) acc = fmaf(W[i * 16 + mm], h[mm], acc);
        yv[i] = acc;
    }

    #pragma unroll
    for (int g = 0; g < LIM / 8; ++g) {   // triangle, 8-wide double-buffered
        float* cur = (g & 1) ? xb : xa;
        float* nxt = (g & 1) ? xa : xb;
        if (g + 1 < LIM / 8) {
            #pragma unroll
            for (int s = 0; s < 8; ++s)
                nxt[s] = xp[(size_t)((g + 1) * 8 + s) * DMODEL];
        }
        #pragma unroll
        for (int s = 0; s < 8; ++s) {
            const int ss = g * 8 + s;
            #pragma unroll
            for (int i = 0; i < QSEG; ++i)
                yv[i] = fmaf(kv[63 + TT * QSEG + i - ss], cur[s], yv[i]);
        }
    }

    float* yp = y + ((size_t)(b * SEQL + j * CT + TT * QSEG)) * DMODEL + d;
    #pragma unroll
    for (int i = 0; i < QSEG; ++i) yp[(size_t)i * DMODEL] = yv[i];
}

__global__ __launch_bounds__(256) void k3_output(const float* __restrict__ x,
                                                 const float* __restrict__ ws,
                                                 float* __restrict__ y) {
    const int blk  = blockIdx.x;          // 2048 blocks
    const int b    = blk >> 9;
    const int j    = (blk >> 4) & 31;
    const int tt   = (blk >> 2) & 3;
    const int dblk = blk & 3;
    const int d    = dblk * 256 + threadIdx.x;

    switch (tt) {                          // wave-uniform branch
        case 0: k3_body<0>(x, ws, y, b, j, d); break;
        case 1: k3_body<1>(x, ws, y, b, j, d); break;
        case 2: k3_body<2>(x, ws, y, b, j, d); break;
        default: k3_body<3>(x, ws, y, b, j, d); break;
    }
}

// ---------------------------------------------------------------------------
extern "C" void kernel_launch(void* const* d_in, const int* in_sizes, int n_in,
                              void* d_out, int out_size, void* d_ws, size_t ws_size,
                              hipStream_t stream) {
    (void)in_sizes; (void)n_in; (void)out_size; (void)ws_size;
    const float* x  = (const float*)d_in[0];
    const float* A  = (const float*)d_in[1];
    const float* Bv = (const float*)d_in[2];
    float* out = (float*)d_out;
    float* ws  = (float*)d_ws;

    // c scratch lives in d_out (overwritten by K3); h_in + tables in ws.
    setup_tables<<<65, 256, 0, stream>>>(A, Bv, ws);
    k1_chunkstate<<<512, 256, 0, stream>>>(x, ws, out);
    k2_carry<<<256, 256, 0, stream>>>(out, ws);
    k3_output<<<2048, 256, 0, stream>>>(x, ws, out);
}